// Round 5
// baseline (78.869 us; speedup 1.0000x reference)
//
#include <hip/hip_runtime.h>

#define B_DIM   1024
#define IN_DIM  1024
#define OUT_DIM 2048
#define NBITS   6
#define NENT    64   // 1 << NBITS

#define OB   256     // o per block (== blockDim.x, o is the lane dim)
#define BB   16      // b per block -> x tile = 64 KB LDS (reuses lut region)
#define LROW 65      // padded lut row stride -> conflict-free own-row read
// LDS: max(OB*LROW, BB*IN_DIM) words = 16640 -> 65 KiB, 2 blocks/CU

// One fused kernel, o in the lane dim (coalesced lut staging, mapping loads,
// out stores). Pipeline per block:
//   1. x tile (16 float4/thread) -> REGISTERS  (loads in flight during 2-4)
//   2. lut tile -> padded LDS, fully coalesced
//   3. each thread pulls ITS row (stride-65: 2-way bank aliasing = free) and
//      finite-difference transforms it in-register to multilinear coeffs
//      (out = sum_S c_S * prod_{j in S} x_mp[j])
//   4. barrier; x regs -> LDS (lut region dead now)
//   5. per b row: 6 random-bank LDS gathers + 63-FMA Horner binary fold,
//      coalesced dword stores.
__global__ __launch_bounds__(256, 2) void lut_fused(
    const float* __restrict__ x,
    const float* __restrict__ lut,
    const int*   __restrict__ mapping,
    float*       __restrict__ out)
{
    __shared__ __align__(16) float smem[OB * LROW];
    const int tid = threadIdx.x;
    const int b0  = blockIdx.x * BB;    // b-tile outer -> same b0 group shares XCD
    const int o0  = blockIdx.y * OB;
    const int o   = o0 + tid;

    // ---- 1. x tile -> registers (latency hidden behind lut staging + FD) ----
    float4 xbuf[16];
    const float4* xsrc = (const float4*)(x + (size_t)b0 * IN_DIM);
#pragma unroll
    for (int i = 0; i < 16; i++) xbuf[i] = xsrc[i * OB + tid];

    // ---- 2. lut tile -> padded LDS (coalesced float4 loads) ----
    const float4* lsrc = (const float4*)(lut + (size_t)o0 * NENT);
#pragma unroll
    for (int i = 0; i < (OB * NENT / 4) / OB; i++) {    // 16 iters
        const int f   = i * OB + tid;                   // float4 index
        const float4 val = lsrc[f];
        const int ow  = f >> 4;                         // 16 float4 per row
        const int kw  = (f & 15) * 4;
        float* d = &smem[ow * LROW + kw];
        d[0] = val.x; d[1] = val.y; d[2] = val.z; d[3] = val.w;
    }

    // ---- my mapping (6 ints, coalesced-ish across lanes) ----
    int mp[NBITS];
#pragma unroll
    for (int j = 0; j < NBITS; j++) mp[j] = mapping[(size_t)o * NBITS + j];

    __syncthreads();

    // ---- 3. pull my lut row + in-register finite-difference transform ----
    float v[NENT];
#pragma unroll
    for (int k = 0; k < NENT; k++) v[k] = smem[tid * LROW + k];
#pragma unroll
    for (int j = 0; j < NBITS; j++) {
#pragma unroll
        for (int k = 0; k < NENT; k++) {
            if ((k >> j) & 1) v[k] -= v[k ^ (1 << j)];
        }
    }

    __syncthreads();   // all lut reads done; region reusable

    // ---- 4. x registers -> LDS ----
    float4* xdst = (float4*)smem;
#pragma unroll
    for (int i = 0; i < 16; i++) xdst[i * OB + tid] = xbuf[i];
    __syncthreads();

    // ---- 5. main loop: 6 LDS gathers + 63-FMA Horner per (b,o) ----
#pragma unroll 2
    for (int bi = 0; bi < BB; bi++) {
        const float* xr = &smem[bi * IN_DIM];           // bi uniform per iter
        float xv[NBITS];
#pragma unroll
        for (int j = 0; j < NBITS; j++) xv[j] = xr[mp[j]];

        float w[NENT / 2];
        {
            const float xj = xv[0];
#pragma unroll
            for (int m = 0; m < NENT / 2; m++)
                w[m] = fmaf(xj, v[2 * m + 1], v[2 * m]);
        }
#pragma unroll
        for (int j = 1; j < NBITS; j++) {
            const float xj = xv[j];
#pragma unroll
            for (int m = 0; m < (NENT >> (j + 1)); m++)
                w[m] = fmaf(xj, w[2 * m + 1], w[2 * m]);
        }
        out[(size_t)(b0 + bi) * OUT_DIM + o] = w[0];
    }
}

extern "C" void kernel_launch(void* const* d_in, const int* in_sizes, int n_in,
                              void* d_out, int out_size, void* d_ws, size_t ws_size,
                              hipStream_t stream) {
    const float* x       = (const float*)d_in[0];
    const float* lut     = (const float*)d_in[1];
    const int*   mapping = (const int*)d_in[2];
    float*       out     = (float*)d_out;
    (void)d_ws; (void)ws_size;

    const dim3 grid(B_DIM / BB, OUT_DIM / OB);   // 64 x 8 = 512 blocks, 2/CU
    lut_fused<<<grid, 256, 0, stream>>>(x, lut, mapping, out);
}

// Round 6
// 69.116 us; speedup vs baseline: 1.1411x; 1.1411x over previous
//
#include <hip/hip_runtime.h>

#define B_DIM   1024
#define IN_DIM  1024
#define OUT_DIM 2048
#define NBITS   6
#define NENT    64   // 1 << NBITS

#define OB   256     // o per block (== blockDim.x)
#define BB   16      // b per block
#define LROW 65      // padded lut row stride in words -> conflict-free row pull
// LDS words needed: max(OB*LROW, BB*IN_DIM) = max(16640, 16384) = 16640 (65 KiB)

// Best measured variant (R3, 69.8 us). Single fused kernel, o in the lane dim
// (coalesced lut staging, mapping loads, out stores). Each thread owns one o:
//   1. lut tile -> padded LDS (coalesced float4 loads),
//   2. pull own row (stride-65: 2-way bank aliasing = free per m136) and
//      finite-difference transform in-register to multilinear coefficients
//      c_S  (out = sum_S c_S * prod_{j in S} x_mp[j]),
//   3. barrier; overwrite LDS with the 16-row x tile (coalesced float4),
//   4. per b row: 6 random-bank LDS gathers + 63-FMA Horner binary fold,
//      coalesced dword stores (full 1KB/wave lines).
// R4 (direct global lut load) and R5 (register-buffered x) both measured
// neutral-to-worse; kept the simplest schedule.
__global__ __launch_bounds__(256, 2) void lut_fused(
    const float* __restrict__ x,
    const float* __restrict__ lut,
    const int*   __restrict__ mapping,
    float*       __restrict__ out)
{
    __shared__ __align__(16) float smem[OB * LROW];
    const int tid = threadIdx.x;
    const int o0  = blockIdx.x * OB;
    const int b0  = blockIdx.y * BB;
    const int o   = o0 + tid;

    // ---- stage lut tile (coalesced float4) into padded LDS ----
    const float4* lsrc = (const float4*)(lut + (size_t)o0 * NENT);
#pragma unroll
    for (int i = 0; i < (OB * NENT / 4) / 256; i++) {   // 16 iters
        const int f   = i * 256 + tid;                  // float4 index
        const float4 val = lsrc[f];
        const int ow  = f >> 4;                         // 16 float4 per row
        const int kw  = (f & 15) * 4;
        float* d = &smem[ow * LROW + kw];               // padded -> scalar stores
        d[0] = val.x; d[1] = val.y; d[2] = val.z; d[3] = val.w;
    }

    // mapping for my o (reused across all b of this block)
    int mp[NBITS];
#pragma unroll
    for (int j = 0; j < NBITS; j++) mp[j] = mapping[(size_t)o * NBITS + j];

    __syncthreads();

    // ---- pull my lut row (stride-65: bank (tid+k)%32, 2 lanes/bank = free) ----
    float v[NENT];
#pragma unroll
    for (int k = 0; k < NENT; k++) v[k] = smem[tid * LROW + k];

    // ---- in-register finite-difference transform: per bit j, hi -= lo ----
#pragma unroll
    for (int j = 0; j < NBITS; j++) {
#pragma unroll
        for (int k = 0; k < NENT; k++) {
            if ((k >> j) & 1) v[k] -= v[k ^ (1 << j)];
        }
    }

    __syncthreads();   // everyone done reading lut region before overwrite

    // ---- stage x tile (BB rows, coalesced float4 -> unpadded LDS) ----
    const float4* xsrc = (const float4*)(x + (size_t)b0 * IN_DIM);
    float4* xdst = (float4*)smem;
#pragma unroll
    for (int i = 0; i < (BB * IN_DIM / 4) / 256; i++) { // 16 iters
        const int f = i * 256 + tid;
        xdst[f] = xsrc[f];
    }
    __syncthreads();

    // ---- main loop: 6 LDS gathers + 63-FMA Horner per output ----
#pragma unroll 4
    for (int bi = 0; bi < BB; bi++) {
        const float* xr = &smem[bi * IN_DIM];           // bi uniform per iter
        float xv[NBITS];
#pragma unroll
        for (int j = 0; j < NBITS; j++) xv[j] = xr[mp[j]];

        float w[NENT / 2];
        {
            const float xj = xv[0];
#pragma unroll
            for (int m = 0; m < NENT / 2; m++)
                w[m] = fmaf(xj, v[2 * m + 1], v[2 * m]);
        }
#pragma unroll
        for (int j = 1; j < NBITS; j++) {
            const float xj = xv[j];
#pragma unroll
            for (int m = 0; m < (NENT >> (j + 1)); m++)
                w[m] = fmaf(xj, w[2 * m + 1], w[2 * m]);
        }
        out[(size_t)(b0 + bi) * OUT_DIM + o] = w[0];
    }
}

extern "C" void kernel_launch(void* const* d_in, const int* in_sizes, int n_in,
                              void* d_out, int out_size, void* d_ws, size_t ws_size,
                              hipStream_t stream) {
    const float* x       = (const float*)d_in[0];
    const float* lut     = (const float*)d_in[1];
    const int*   mapping = (const int*)d_in[2];
    float*       out     = (float*)d_out;
    (void)d_ws; (void)ws_size;

    const dim3 grid(OUT_DIM / OB, B_DIM / BB);   // 8 x 64 = 512 blocks, 2/CU
    lut_fused<<<grid, 256, 0, stream>>>(x, lut, mapping, out);
}